// Round 1
// baseline (506.335 us; speedup 1.0000x reference)
//
#include <hip/hip_runtime.h>
#include <math.h>

#define SEQ 577
#define NH 12
#define DH 64
#define EMB 768
#define NBATCH 16
#define NC 2
#define BC (NBATCH/NC)
#define MC (BC*SEQ)      // 4616 rows per chunk
#define BHC (BC*NH)      // 96 (b,h) per chunk
#define VTS 592          // vt row stride in m (16 ushort aligned, >= 577)
#define KAUGR 640        // kaug rows (phase A/C read m up to 639; rows >=577 zero)

typedef float f32x4 __attribute__((ext_vector_type(4)));
typedef short s16x8 __attribute__((ext_vector_type(8)));

__device__ __forceinline__ float bf2f(unsigned short u) {
  union { unsigned int i; float f; } c; c.i = ((unsigned int)u) << 16; return c.f;
}
__device__ __forceinline__ unsigned short f2bf(float f) {
  union { float f; unsigned int i; } c; c.f = f;
  unsigned int r = c.i + 0x7FFFu + ((c.i >> 16) & 1u);   // round-nearest-even
  return (unsigned short)(r >> 16);
}

// Async global->LDS, 16B per lane. LDS dest is wave-uniform base + lane*16.
__device__ __forceinline__ void gl_lds16(const unsigned short* g, unsigned short* l) {
  __builtin_amdgcn_global_load_lds(
      (const __attribute__((address_space(1))) unsigned int*)g,
      (__attribute__((address_space(3))) unsigned int*)l, 16, 0, 0);
}

// ---------------------------------------------------------------------------
__global__ __launch_bounds__(256) void cast_kernel(
    const float* __restrict__ s, unsigned short* __restrict__ d, int n4)
{
  int i = blockIdx.x * 256 + threadIdx.x;
  if (i < n4) {
    float4 v = *(const float4*)&s[(size_t)i*4];
    ushort4 o; o.x = f2bf(v.x); o.y = f2bf(v.y); o.z = f2bf(v.z); o.w = f2bf(v.w);
    *(ushort4*)&d[(size_t)i*4] = o;
  }
}

// ---------------------------------------------------------------------------
// One-time table builder (data-independent except vtt):
//  kaug  [640][64] bf16: row m = onehot(xm)(c 0..23) | onehot(ym)(c 24..47) |
//                        cls flags (c 48,49 for m==0); rows >=577 zero.
//  kaugT [64][640]     : transpose of kaug (B-frag layout for the W-MFMA).
//  vtt   [64][128] bf16: VTT[d][j] = vx_emb[j][d]     (d<32,  j<50)
//                                   = vy_emb[j-64][d-32](d>=32, 64<=j<114), else 0.
// ---------------------------------------------------------------------------
__global__ __launch_bounds__(256) void build_tables_kernel(
    const float* __restrict__ vxe, const float* __restrict__ vye,
    unsigned short* __restrict__ kaug, unsigned short* __restrict__ kaugT,
    unsigned short* __restrict__ vtt)
{
  int t = blockIdx.x * 256 + threadIdx.x;
  const unsigned short ONE = 0x3F80;   // bf16 1.0
  if (t < KAUGR * 64) {
    int m = t >> 6, c = t & 63;
    unsigned short v = 0;
    if (m == 0) {
      if (c == 48 || c == 49) v = ONE;
    } else if (m < SEQ) {
      int xm = (m - 1) % 24, ym = (m - 1) / 24;
      if (c == xm || c == 24 + ym) v = ONE;
    }
    kaug[m*64 + c] = v;
    kaugT[(size_t)c*KAUGR + m] = v;
  } else {
    int u = t - KAUGR*64;
    if (u < 64*128) {
      int d = u >> 7, j = u & 127;
      float f = 0.f;
      if (d < 32) { if (j < 50) f = vxe[j*32 + d]; }
      else        { if (j >= 64 && j < 114) f = vye[(j-64)*32 + (d-32)]; }
      vtt[d*128 + j] = f2bf(f);
    }
  }
}

// ---------------------------------------------------------------------------
// bf16 MFMA GEMM (NT), m97-style global_load_lds staging (width=16).
// ---------------------------------------------------------------------------
#define GT 128
__global__ __launch_bounds__(256) void gemm_bf16(
    const unsigned short* __restrict__ A, const unsigned short* __restrict__ Bm,
    unsigned short* __restrict__ Cq, unsigned short* __restrict__ Ck,
    unsigned short* __restrict__ Cv, float* __restrict__ Cf,
    int M, int N, int mode)
{
  __shared__ __align__(16) unsigned short AsF[GT*32];
  __shared__ __align__(16) unsigned short BsF[GT*32];
  const int tid = threadIdx.x;
  const int wave = tid >> 6;
  const int lane = tid & 63;
  const int wr = wave >> 1, wc = wave & 1;
  const int li = lane & 15, g = lane >> 4;
  const int r0 = blockIdx.y * GT, c0 = blockIdx.x * GT;

  const int row1 = tid >> 2,          seg1 = tid & 3;
  const int row2 = (tid + 256) >> 2,  seg2 = tid & 3;
  const unsigned short* ga1 = &A [(size_t)(r0 + row1)*EMB + seg1*8];
  const unsigned short* ga2 = &A [(size_t)(r0 + row2)*EMB + seg2*8];
  const unsigned short* gb1 = &Bm[(size_t)(c0 + row1)*EMB + seg1*8];
  const unsigned short* gb2 = &Bm[(size_t)(c0 + row2)*EMB + seg2*8];
  unsigned short* la1 = &AsF[wave*512];
  unsigned short* la2 = &AsF[2048 + wave*512];
  unsigned short* lb1 = &BsF[wave*512];
  unsigned short* lb2 = &BsF[2048 + wave*512];

  f32x4 acc[4][4];
#pragma unroll
  for (int i = 0; i < 4; ++i)
#pragma unroll
    for (int j = 0; j < 4; ++j) { acc[i][j][0]=0.f; acc[i][j][1]=0.f; acc[i][j][2]=0.f; acc[i][j][3]=0.f; }

  for (int k0 = 0; k0 < EMB; k0 += 32) {
    gl_lds16(ga1 + k0, la1);
    gl_lds16(ga2 + k0, la2);
    gl_lds16(gb1 + k0, lb1);
    gl_lds16(gb2 + k0, lb2);
    __syncthreads();

    s16x8 af[4], bfv[4];
#pragma unroll
    for (int i = 0; i < 4; ++i) af[i]  = *(const s16x8*)&AsF[(wr*64 + i*16 + li)*32 + g*8];
#pragma unroll
    for (int j = 0; j < 4; ++j) bfv[j] = *(const s16x8*)&BsF[(wc*64 + j*16 + li)*32 + g*8];
#pragma unroll
    for (int i = 0; i < 4; ++i)
#pragma unroll
      for (int j = 0; j < 4; ++j)
        acc[i][j] = __builtin_amdgcn_mfma_f32_16x16x32_bf16(af[i], bfv[j], acc[i][j], 0, 0, 0);
    __syncthreads();
  }

#pragma unroll
  for (int i = 0; i < 4; ++i) {
    int rbase = r0 + wr*64 + i*16 + g*4;
#pragma unroll
    for (int j = 0; j < 4; ++j) {
      int col = c0 + wc*64 + j*16 + li;
#pragma unroll
      for (int rg = 0; rg < 4; ++rg) {
        int gr = rbase + rg;
        if (gr >= M) continue;
        float val = acc[i][j][rg];
        if (mode == 1) {
          Cf[(size_t)gr*N + col] = val;
        } else {
          int t  = col / EMB;
          int ct = col - t*EMB;
          int h  = ct >> 6, dd = ct & 63;
          int brow = gr / SEQ, nrow = gr - brow*SEQ;
          if (t == 0)
            Cq[(((size_t)brow*NH + h)*SEQ + nrow)*DH + dd] = f2bf(val);
          else if (t == 1)
            Ck[(((size_t)brow*NH + h)*SEQ + nrow)*DH + dd] = f2bf(val);
          else
            Cv[(((size_t)brow*NH + h)*DH + dd)*VTS + nrow] = f2bf(val);
        }
      }
    }
  }
}

// ---------------------------------------------------------------------------
// MFMA fused attention, bias-as-MFMA redesign:
//  * QK^T bias fused via augmented K=128 MFMA chain: qf2/qf3 = QA (row-shifted
//    qx/qy dot tables), kf2/kf3 = kaug one-hot. Kills 80 LDS gathers + ~450
//    VALU per wave in phase A.
//  * Column/row sums W = P @ kaug via 2 extra MFMAs per PV step (reuses P
//    A-frags). Kills the CS scalar-gather loop.
//  * v-bias = Wrel @ VTT via 4 MFMAs. Kills the 96-fmaf 4-way-conflicted
//    epilogue gather and the 12.8 KB VXL/VYL staging.
// LDS: Ps 18688 + U(union 8704) + red 256 = 27648 B -> 5 blocks/CU.
// ---------------------------------------------------------------------------
#define TRB 16
#define SW 584

#define FOR_KT(X) X(0,s0) X(1,s1) X(2,s2) X(3,s3) X(4,s4) \
                  X(5,s5) X(6,s6) X(7,s7) X(8,s8) X(9,s9)

__global__ __launch_bounds__(256) void attn_kernel(
    const unsigned short* __restrict__ qg, const unsigned short* __restrict__ kg,
    const unsigned short* __restrict__ vtg,
    const float* __restrict__ qxe, const float* __restrict__ qye,
    const unsigned short* __restrict__ kaug, const unsigned short* __restrict__ kaugT,
    const unsigned short* __restrict__ vtt,
    unsigned short* __restrict__ og)
{
  __shared__ __align__(16) unsigned short Ps[TRB][SW];
  __shared__ __align__(16) unsigned char  U[8704];
  __shared__ __align__(16) float red[TRB][4];

  // stage 1 (dead after phase-A frag load):
  unsigned short* TB   = (unsigned short*)U;            // [16][100] qx/qy dot tables
  unsigned short* QA   = (unsigned short*)(U + 3200);   // [16][80]  row-shifted bias A-operand
  // stage 2 (written after barrier b5, so no overlap hazard):
  float*          Wf   = (float*)U;                     // [16][68]  W = P @ kaug (fp32)
  unsigned short* Wrel = (unsigned short*)(U + 4352);   // [16][136] per-row shifted W (bf16)

  const int tid  = threadIdx.x;
  const int wave = tid >> 6, lane = tid & 63;
  const int li = lane & 15, gg = lane >> 4;
  const int bh = blockIdx.y;
  const int r0 = blockIdx.x * TRB;
  const size_t qkbase = (size_t)bh * SEQ * DH;
  const size_t vtbase = (size_t)bh * DH * VTS;
  const s16x8 z8 = {0,0,0,0,0,0,0,0};

  // ---- Q A-frags from global (resident through phase A) ----
  s16x8 qf0, qf1;
  {
    int n = r0 + li;
    qf0 = (n < SEQ) ? *(const s16x8*)&qg[qkbase + (size_t)n*DH + gg*8] : z8;
    qf1 = (n < SEQ) ? *(const s16x8*)&qg[qkbase + (size_t)n*DH + 32 + gg*8] : z8;
  }

  // ---- bias dot tables via MFMA: qx_dot/qy_dot [16 rows][50 bins] bf16 ----
  {
    int bin = wave*16 + li;
    s16x8 bx = z8, by = z8;
    if (bin < 50) {
      float4 x0 = *(const float4*)&qxe[bin*32 + gg*8];
      float4 x1 = *(const float4*)&qxe[bin*32 + gg*8 + 4];
      float4 y0 = *(const float4*)&qye[bin*32 + gg*8];
      float4 y1 = *(const float4*)&qye[bin*32 + gg*8 + 4];
      bx[0]=f2bf(x0.x); bx[1]=f2bf(x0.y); bx[2]=f2bf(x0.z); bx[3]=f2bf(x0.w);
      bx[4]=f2bf(x1.x); bx[5]=f2bf(x1.y); bx[6]=f2bf(x1.z); bx[7]=f2bf(x1.w);
      by[0]=f2bf(y0.x); by[1]=f2bf(y0.y); by[2]=f2bf(y0.z); by[3]=f2bf(y0.w);
      by[4]=f2bf(y1.x); by[5]=f2bf(y1.y); by[6]=f2bf(y1.z); by[7]=f2bf(y1.w);
    }
    f32x4 ax0={0.f,0.f,0.f,0.f}, ay0={0.f,0.f,0.f,0.f};
    ax0 = __builtin_amdgcn_mfma_f32_16x16x32_bf16(qf0, bx, ax0, 0,0,0);
    ay0 = __builtin_amdgcn_mfma_f32_16x16x32_bf16(qf1, by, ay0, 0,0,0);
    if (bin < 50) {
#pragma unroll
      for (int rg = 0; rg < 4; ++rg) {
        TB[(gg*4+rg)*100      + bin] = f2bf(ax0[rg]);
        TB[(gg*4+rg)*100 + 50 + bin] = f2bf(ay0[rg]);
      }
    }
  }
  __syncthreads();   // b1: TB ready

  // ---- build QA[r][c]: QA pairs with kaug one-hot so that
  //      sum_c QA[n][c]*kaug[m][c] == qx_dot[n,xi(n,m)] + qy_dot[n,yi(n,m)] ----
  for (int task = tid; task < TRB*64; task += 256) {
    int r = task >> 6, c = task & 63;
    int nn = r0 + r;
    unsigned short v;
    if (c < 24) {
      int idx = 0;                                    // n==0 (or OOB row): bin 0
      if (nn > 0 && nn < SEQ) idx = c - ((nn-1) % 24) + 25;
      v = TB[r*100 + idx];
    } else if (c < 48) {
      int idx = 0;
      if (nn > 0 && nn < SEQ) idx = (c - 24) - ((nn-1) / 24) + 25;
      v = TB[r*100 + 50 + idx];
    } else if (c == 48) v = TB[r*100];                // cls-column x term
    else if (c == 49)   v = TB[r*100 + 50];           // cls-column y term
    else v = 0;
    QA[r*80 + c] = v;
  }
  __syncthreads();   // b2: QA ready

  s16x8 qf2 = *(const s16x8*)&QA[li*80 + gg*8];
  s16x8 qf3 = *(const s16x8*)&QA[li*80 + 32 + gg*8];

  // ---- Phase A: (QK^T + bias) via K=128 MFMA chain; NO barriers ----
  const unsigned short* kwv  = &kg[qkbase + (size_t)(wave*16 + li)*DH];
  const unsigned short* kawv = &kaug[(size_t)(wave*16 + li)*64];
#define DECLS(KT, SA) f32x4 SA;
  FOR_KT(DECLS)
#undef DECLS

#define KTSTEP(KT, SA) do {                                                   \
    const int m0_ = (KT)*64;                                                  \
    s16x8 kf0_ = *(const s16x8*)&kwv[(size_t)m0_*DH + gg*8];                  \
    s16x8 kf1_ = *(const s16x8*)&kwv[(size_t)m0_*DH + 32 + gg*8];             \
    s16x8 kf2_ = *(const s16x8*)&kawv[(size_t)m0_*64 + gg*8];                 \
    s16x8 kf3_ = *(const s16x8*)&kawv[(size_t)m0_*64 + 32 + gg*8];            \
    f32x4 a0_ = {0.f,0.f,0.f,0.f};                                            \
    a0_ = __builtin_amdgcn_mfma_f32_16x16x32_bf16(qf0, kf0_, a0_, 0,0,0);     \
    a0_ = __builtin_amdgcn_mfma_f32_16x16x32_bf16(qf1, kf1_, a0_, 0,0,0);     \
    a0_ = __builtin_amdgcn_mfma_f32_16x16x32_bf16(qf2, kf2_, a0_, 0,0,0);     \
    a0_ = __builtin_amdgcn_mfma_f32_16x16x32_bf16(qf3, kf3_, a0_, 0,0,0);     \
    const int m_ = m0_ + wave*16 + li;                                        \
    _Pragma("unroll")                                                         \
    for (int rg = 0; rg < 4; ++rg)                                            \
      SA[rg] = (m_ < SEQ) ? a0_[rg] * 0.125f : -INFINITY;                     \
  } while (0);
  FOR_KT(KTSTEP)
#undef KTSTEP

  // ---- Phase B: softmax (named regs) -> Ps bf16; row sums in red ----
  f32x4 mxA = s0;
#define MAXST(KT, SA) if ((KT) > 0) {                                         \
    _Pragma("unroll")                                                         \
    for (int rg = 0; rg < 4; ++rg) mxA[rg] = fmaxf(mxA[rg], SA[rg]); }
  FOR_KT(MAXST)
#undef MAXST

  float MA[4];
#pragma unroll
  for (int rg = 0; rg < 4; ++rg) {
    float mx = mxA[rg];
    mx = fmaxf(mx, __shfl_xor(mx, 1));
    mx = fmaxf(mx, __shfl_xor(mx, 2));
    mx = fmaxf(mx, __shfl_xor(mx, 4));
    mx = fmaxf(mx, __shfl_xor(mx, 8));
    if (li == 0) red[gg*4 + rg][wave] = mx;
  }
  __syncthreads();   // b3: per-wave maxes
#pragma unroll
  for (int rg = 0; rg < 4; ++rg) {
    float4 ra = *(float4*)&red[gg*4 + rg][0];
    MA[rg] = fmaxf(fmaxf(ra.x, ra.y), fmaxf(ra.z, ra.w));
  }
  __syncthreads();   // b4: max reads done before red reuse

  f32x4 LpA = {0.f,0.f,0.f,0.f};
#define PROBST(KT, SA) {                                                      \
    int col_ = (KT)*64 + wave*16 + li;                                        \
    _Pragma("unroll")                                                         \
    for (int rg = 0; rg < 4; ++rg) {                                          \
      float p_ = __expf(SA[rg] - MA[rg]);                                     \
      LpA[rg] += p_;                                                          \
      if (col_ < SW) Ps[gg*4 + rg][col_] = f2bf(p_);                          \
    } }
  FOR_KT(PROBST)
#undef PROBST

#pragma unroll
  for (int rg = 0; rg < 4; ++rg) {
    float s = LpA[rg];
    s += __shfl_xor(s, 1); s += __shfl_xor(s, 2);
    s += __shfl_xor(s, 4); s += __shfl_xor(s, 8);
    if (li == 0) red[gg*4 + rg][wave] = s;
  }
  __syncthreads();   // b5: Ps complete; red sums ready; stage-1 U dead

  // ---- Phase C: O = P.V and W = P.kaug via MFMA from global; NO barriers ----
  const unsigned short* vwv = &vtg[vtbase + (size_t)(wave*16 + li)*VTS];
  const unsigned short* ktv = &kaugT[(size_t)(wave*16 + li)*KAUGR];
  f32x4 oa0  = {0.f,0.f,0.f,0.f};
  f32x4 wacc = {0.f,0.f,0.f,0.f};
#pragma unroll
  for (int vt = 0; vt < 10; ++vt) {
    int m0 = vt*64;
    s16x8 vf0 = *(const s16x8*)&vwv[m0 + gg*8];
    s16x8 vf1 = *(const s16x8*)&vwv[m0 + 32 + gg*8];
    s16x8 kt0 = *(const s16x8*)&ktv[m0 + gg*8];
    s16x8 kt1 = *(const s16x8*)&ktv[m0 + 32 + gg*8];
    s16x8 af00, af01;
    if (vt < 9) {
      af00 = *(const s16x8*)&Ps[li][m0 + gg*8];
      af01 = *(const s16x8*)&Ps[li][m0 + 32 + gg*8];
    } else {
      af00 = (gg == 0) ? *(const s16x8*)&Ps[li][576] : z8;   // probs 577..583 = 0
      af01 = z8;
    }
    oa0  = __builtin_amdgcn_mfma_f32_16x16x32_bf16(af00, vf0, oa0, 0,0,0);
    oa0  = __builtin_amdgcn_mfma_f32_16x16x32_bf16(af01, vf1, oa0, 0,0,0);
    wacc = __builtin_amdgcn_mfma_f32_16x16x32_bf16(af00, kt0, wacc, 0,0,0);
    wacc = __builtin_amdgcn_mfma_f32_16x16x32_bf16(af01, kt1, wacc, 0,0,0);
  }
#pragma unroll
  for (int rg = 0; rg < 4; ++rg)
    Wf[(gg*4 + rg)*68 + wave*16 + li] = wacc[rg];
  __syncthreads();   // b6: Wf ready

  // ---- build Wrel[r][j]: per-row shift of W into relative bins (x: j 0..49,
  //      y: j 64..113). j==0/64 carry the cls term (n==0: full row sum Lr). ----
  for (int task = tid; task < TRB*128; task += 256) {
    int r = task >> 7, j = task & 127;
    int nn = r0 + r;
    float v = 0.f;
    if (j == 0 || j == 64) {
      if (nn == 0) { float4 r4 = *(float4*)&red[r][0]; v = r4.x + r4.y + r4.z + r4.w; }
      else         v = Wf[r*68 + 48 + (j >> 6)];
    } else if (j < 50) {
      if (nn > 0) {
        int xn_ = (nn < SEQ) ? (nn-1) % 24 : 0;
        int c = j + xn_ - 25;
        if (c >= 0 && c < 24) v = Wf[r*68 + c];
      }
    } else if (j >= 65 && j < 114) {
      if (nn > 0) {
        int yn_ = (nn < SEQ) ? (nn-1) / 24 : 0;
        int c = (j - 64) + yn_ - 25;
        if (c >= 0 && c < 24) v = Wf[r*68 + 24 + c];
      }
    }
    Wrel[r*136 + j] = f2bf(v);
  }
  __syncthreads();   // b7: Wrel ready

  // ---- v-bias via K=128 MFMA: bias[n][d] = sum_j Wrel[n][j]*VTT[j][d];
  //      then epilogue: o = (oa0 + bias)/Lr, write bf16 (B,N,H,D) ----
  {
    const unsigned short* vtw = &vtt[(size_t)(wave*16 + li)*128];
    f32x4 bacc = {0.f,0.f,0.f,0.f};
#pragma unroll
    for (int ko = 0; ko < 4; ++ko) {
      s16x8 wa = *(const s16x8*)&Wrel[li*136 + ko*32 + gg*8];
      s16x8 wb = *(const s16x8*)&vtw[ko*32 + gg*8];
      bacc = __builtin_amdgcn_mfma_f32_16x16x32_bf16(wa, wb, bacc, 0,0,0);
    }
    int d = wave*16 + li;
    int bI = bh / NH, hI = bh - bI*NH;
#pragma unroll
    for (int rg = 0; rg < 4; ++rg) {
      int nloc = gg*4 + rg;
      int n = r0 + nloc;
      if (n >= SEQ) continue;
      float4 r4 = *(float4*)&red[nloc][0];
      float Lr = r4.x + r4.y + r4.z + r4.w;
      og[(((size_t)bI*SEQ + n)*NH + hI)*DH + d] = f2bf((oa0[rg] + bacc[rg]) / Lr);
    }
  }
}

// ---------------------------------------------------------------------------
// ws (ushorts): q 3.545M, k 3.545M, vt 3.637M, ows 3.545M, xbf 3.545M,
// wqkv 1.769M, wproj 0.590M, kaug 40960, kaugT 40960, vtt 8192
// => ~40.5 MB total (< 56.7 MB proven budget).
// ---------------------------------------------------------------------------
extern "C" void kernel_launch(void* const* d_in, const int* in_sizes, int n_in,
                              void* d_out, int out_size, void* d_ws, size_t ws_size,
                              hipStream_t stream)
{
  const float* x     = (const float*)d_in[0];
  const float* qkvw  = (const float*)d_in[1];
  const float* projw = (const float*)d_in[2];
  const float* qxe   = (const float*)d_in[3];
  const float* qye   = (const float*)d_in[4];
  const float* vxe   = (const float*)d_in[5];
  const float* vye   = (const float*)d_in[6];
  float* out = (float*)d_out;

  const size_t SLc = (size_t)BHC * SEQ * DH;        // 3,545,088
  const size_t VTL = (size_t)BHC * DH * VTS;        // 3,637,248
  unsigned short* qws     = (unsigned short*)d_ws;
  unsigned short* kws     = qws + SLc;
  unsigned short* vtws    = kws + SLc;
  unsigned short* ows     = vtws + VTL;
  unsigned short* xbf     = ows + SLc;
  unsigned short* wqkv    = xbf + SLc;
  unsigned short* wproj   = wqkv + (size_t)3*EMB*EMB;
  unsigned short* kaugws  = wproj + (size_t)EMB*EMB;
  unsigned short* kaugTws = kaugws + (size_t)KAUGR*64;
  unsigned short* vttws   = kaugTws + (size_t)64*KAUGR;

  cast_kernel<<<(3*EMB*EMB/4 + 255)/256, 256, 0, stream>>>(qkvw, wqkv, 3*EMB*EMB/4);
  cast_kernel<<<(EMB*EMB/4 + 255)/256, 256, 0, stream>>>(projw, wproj, EMB*EMB/4);
  build_tables_kernel<<<(KAUGR*64 + 64*128 + 255)/256, 256, 0, stream>>>(
      vxe, vye, kaugws, kaugTws, vttws);

  dim3 g1(3*EMB/GT, (MC + GT - 1)/GT);   // 18 x 37
  dim3 g2((SEQ + TRB - 1)/TRB, BHC);     // 37 x 96
  dim3 g3(EMB/GT, (MC + GT - 1)/GT);     // 6 x 37

  for (int c = 0; c < NC; ++c) {
    const float* xc = x   + (size_t)c * MC * EMB;
    float*       oc = out + (size_t)c * MC * EMB;
    cast_kernel<<<(MC*EMB/4 + 255)/256, 256, 0, stream>>>(xc, xbf, MC*EMB/4);
    gemm_bf16<<<g1, 256, 0, stream>>>(xbf, wqkv, qws, kws, vtws, nullptr, MC, 3*EMB, 0);
    attn_kernel<<<g2, 256, 0, stream>>>(qws, kws, vtws, qxe, qye,
                                        kaugws, kaugTws, vttws, ows);
    gemm_bf16<<<g3, 256, 0, stream>>>(ows, wproj, nullptr, nullptr, nullptr, oc, MC, EMB, 1);
  }
}

// Round 2
// 495.129 us; speedup vs baseline: 1.0226x; 1.0226x over previous
//
#include <hip/hip_runtime.h>
#include <math.h>

#define SEQ 577
#define NH 12
#define DH 64
#define EMB 768
#define NBATCH 16
#define NC 2
#define BC (NBATCH/NC)
#define MC (BC*SEQ)      // 4616 rows per chunk
#define BHC (BC*NH)      // 96 (b,h) per chunk
#define VTS 592          // vt row stride in m (16 ushort aligned, >= 577)
#define KAUGR 640        // kaugT cols (phase C reads m up to 639; cols >=577 zero)

typedef float f32x4 __attribute__((ext_vector_type(4)));
typedef short s16x8 __attribute__((ext_vector_type(8)));

__device__ __forceinline__ float bf2f(unsigned short u) {
  union { unsigned int i; float f; } c; c.i = ((unsigned int)u) << 16; return c.f;
}
__device__ __forceinline__ unsigned short f2bf(float f) {
  union { float f; unsigned int i; } c; c.f = f;
  unsigned int r = c.i + 0x7FFFu + ((c.i >> 16) & 1u);   // round-nearest-even
  return (unsigned short)(r >> 16);
}

// Async global->LDS, 16B per lane. LDS dest is wave-uniform base + lane*16.
__device__ __forceinline__ void gl_lds16(const unsigned short* g, unsigned short* l) {
  __builtin_amdgcn_global_load_lds(
      (const __attribute__((address_space(1))) unsigned int*)g,
      (__attribute__((address_space(3))) unsigned int*)l, 16, 0, 0);
}

// ---------------------------------------------------------------------------
__global__ __launch_bounds__(256) void cast_kernel(
    const float* __restrict__ s, unsigned short* __restrict__ d, int n4)
{
  int i = blockIdx.x * 256 + threadIdx.x;
  if (i < n4) {
    float4 v = *(const float4*)&s[(size_t)i*4];
    ushort4 o; o.x = f2bf(v.x); o.y = f2bf(v.y); o.z = f2bf(v.z); o.w = f2bf(v.w);
    *(ushort4*)&d[(size_t)i*4] = o;
  }
}

// ---------------------------------------------------------------------------
// One-time table builder (data-independent except vtt):
//  kaugT [64][640] bf16: kaugT[c][m] = onehot row m: 1.0 at c==xm, c==24+ym
//                        (m>0), c==48/49 for m==0; cols >=577 zero.
//  vtt   [64][128] bf16: VTT[d][j] = vx_emb[j][d]      (d<32,  j<50)
//                                   = vy_emb[j-64][d-32] (d>=32, 64<=j<114), else 0.
// ---------------------------------------------------------------------------
__global__ __launch_bounds__(256) void build_tables_kernel(
    const float* __restrict__ vxe, const float* __restrict__ vye,
    unsigned short* __restrict__ kaugT, unsigned short* __restrict__ vtt)
{
  int t = blockIdx.x * 256 + threadIdx.x;
  const unsigned short ONE = 0x3F80;   // bf16 1.0
  if (t < KAUGR * 64) {
    int m = t >> 6, c = t & 63;
    unsigned short v = 0;
    if (m == 0) {
      if (c == 48 || c == 49) v = ONE;
    } else if (m < SEQ) {
      int xm = (m - 1) % 24, ym = (m - 1) / 24;
      if (c == xm || c == 24 + ym) v = ONE;
    }
    kaugT[(size_t)c*KAUGR + m] = v;
  } else {
    int u = t - KAUGR*64;
    if (u < 64*128) {
      int d = u >> 7, j = u & 127;
      float f = 0.f;
      if (d < 32) { if (j < 50) f = vxe[j*32 + d]; }
      else        { if (j >= 64 && j < 114) f = vye[(j-64)*32 + (d-32)]; }
      vtt[d*128 + j] = f2bf(f);
    }
  }
}

// ---------------------------------------------------------------------------
// bf16 MFMA GEMM (NT), m97-style global_load_lds staging (width=16).
// ---------------------------------------------------------------------------
#define GT 128
__global__ __launch_bounds__(256) void gemm_bf16(
    const unsigned short* __restrict__ A, const unsigned short* __restrict__ Bm,
    unsigned short* __restrict__ Cq, unsigned short* __restrict__ Ck,
    unsigned short* __restrict__ Cv, float* __restrict__ Cf,
    int M, int N, int mode)
{
  __shared__ __align__(16) unsigned short AsF[GT*32];
  __shared__ __align__(16) unsigned short BsF[GT*32];
  const int tid = threadIdx.x;
  const int wave = tid >> 6;
  const int lane = tid & 63;
  const int wr = wave >> 1, wc = wave & 1;
  const int li = lane & 15, g = lane >> 4;
  const int r0 = blockIdx.y * GT, c0 = blockIdx.x * GT;

  const int row1 = tid >> 2,          seg1 = tid & 3;
  const int row2 = (tid + 256) >> 2,  seg2 = tid & 3;
  const unsigned short* ga1 = &A [(size_t)(r0 + row1)*EMB + seg1*8];
  const unsigned short* ga2 = &A [(size_t)(r0 + row2)*EMB + seg2*8];
  const unsigned short* gb1 = &Bm[(size_t)(c0 + row1)*EMB + seg1*8];
  const unsigned short* gb2 = &Bm[(size_t)(c0 + row2)*EMB + seg2*8];
  unsigned short* la1 = &AsF[wave*512];
  unsigned short* la2 = &AsF[2048 + wave*512];
  unsigned short* lb1 = &BsF[wave*512];
  unsigned short* lb2 = &BsF[2048 + wave*512];

  f32x4 acc[4][4];
#pragma unroll
  for (int i = 0; i < 4; ++i)
#pragma unroll
    for (int j = 0; j < 4; ++j) { acc[i][j][0]=0.f; acc[i][j][1]=0.f; acc[i][j][2]=0.f; acc[i][j][3]=0.f; }

  for (int k0 = 0; k0 < EMB; k0 += 32) {
    gl_lds16(ga1 + k0, la1);
    gl_lds16(ga2 + k0, la2);
    gl_lds16(gb1 + k0, lb1);
    gl_lds16(gb2 + k0, lb2);
    __syncthreads();

    s16x8 af[4], bfv[4];
#pragma unroll
    for (int i = 0; i < 4; ++i) af[i]  = *(const s16x8*)&AsF[(wr*64 + i*16 + li)*32 + g*8];
#pragma unroll
    for (int j = 0; j < 4; ++j) bfv[j] = *(const s16x8*)&BsF[(wc*64 + j*16 + li)*32 + g*8];
#pragma unroll
    for (int i = 0; i < 4; ++i)
#pragma unroll
      for (int j = 0; j < 4; ++j)
        acc[i][j] = __builtin_amdgcn_mfma_f32_16x16x32_bf16(af[i], bfv[j], acc[i][j], 0, 0, 0);
    __syncthreads();
  }

#pragma unroll
  for (int i = 0; i < 4; ++i) {
    int rbase = r0 + wr*64 + i*16 + g*4;
#pragma unroll
    for (int j = 0; j < 4; ++j) {
      int col = c0 + wc*64 + j*16 + li;
#pragma unroll
      for (int rg = 0; rg < 4; ++rg) {
        int gr = rbase + rg;
        if (gr >= M) continue;
        float val = acc[i][j][rg];
        if (mode == 1) {
          Cf[(size_t)gr*N + col] = val;
        } else {
          int t  = col / EMB;
          int ct = col - t*EMB;
          int h  = ct >> 6, dd = ct & 63;
          int brow = gr / SEQ, nrow = gr - brow*SEQ;
          if (t == 0)
            Cq[(((size_t)brow*NH + h)*SEQ + nrow)*DH + dd] = f2bf(val);
          else if (t == 1)
            Ck[(((size_t)brow*NH + h)*SEQ + nrow)*DH + dd] = f2bf(val);
          else
            Cv[(((size_t)brow*NH + h)*DH + dd)*VTS + nrow] = f2bf(val);
        }
      }
    }
  }
}

// ---------------------------------------------------------------------------
// MFMA fused attention — hybrid of round-8 (110us) phase A and the bias-as-
// MFMA epilogue:
//  * Phase A: TB-gather form (LDS-resident, overlappable) — the kaug global
//    augmentation regressed (latency chain), reverted. TB stride padded to
//    104 (y at +52) to de-alias gather banks.
//  * Phase C: W = P @ kaugT via 2 extra MFMAs per step (reuses P A-frags) —
//    kills the CS scalar loop.
//  * Epilogue: v-bias = Wrel @ VTT via 4 MFMAs — kills the 96-fmaf conflicted
//    gather AND the 12.8KB VXL/VYL staging.
// LDS: Ps 18688 + U 8704 + red 256 = 27648 B -> 5 blocks/CU.
// ---------------------------------------------------------------------------
#define TRB 16
#define SW 584

#define FOR_KT(X) X(0,s0) X(1,s1) X(2,s2) X(3,s3) X(4,s4) \
                  X(5,s5) X(6,s6) X(7,s7) X(8,s8) X(9,s9)

__global__ __launch_bounds__(256) void attn_kernel(
    const unsigned short* __restrict__ qg, const unsigned short* __restrict__ kg,
    const unsigned short* __restrict__ vtg,
    const float* __restrict__ qxe, const float* __restrict__ qye,
    const unsigned short* __restrict__ kaugT, const unsigned short* __restrict__ vtt,
    unsigned short* __restrict__ og)
{
  __shared__ __align__(16) unsigned short Ps[TRB][SW];
  __shared__ __align__(16) unsigned char  U[8704];
  __shared__ __align__(16) float red[TRB][4];

  // stage 1 (dead after phase A): TB [16][104] bf16, x bins 0..49 at +0,
  //                               y bins at +52.
  unsigned short* TB   = (unsigned short*)U;
  // stage 2 (written after barrier b4): Wf [16][68] f32, Wrel [16][136] bf16.
  float*          Wf   = (float*)U;
  unsigned short* Wrel = (unsigned short*)(U + 4352);

  const int tid  = threadIdx.x;
  const int wave = tid >> 6, lane = tid & 63;
  const int li = lane & 15, gg = lane >> 4;
  const int bh = blockIdx.y;
  const int r0 = blockIdx.x * TRB;
  const size_t qkbase = (size_t)bh * SEQ * DH;
  const size_t vtbase = (size_t)bh * DH * VTS;
  const s16x8 z8 = {0,0,0,0,0,0,0,0};

  // ---- Q A-frags from global (kept resident through phase A) ----
  s16x8 qf0, qf1;
  {
    int n = r0 + li;
    qf0 = (n < SEQ) ? *(const s16x8*)&qg[qkbase + (size_t)n*DH + gg*8] : z8;
    qf1 = (n < SEQ) ? *(const s16x8*)&qg[qkbase + (size_t)n*DH + 32 + gg*8] : z8;
  }

  // ---- bias dot tables via MFMA: qx_dot/qy_dot [16 rows][50 bins] bf16 ----
  {
    int bin = wave*16 + li;
    s16x8 bx = z8, by = z8;
    if (bin < 50) {
      float4 x0 = *(const float4*)&qxe[bin*32 + gg*8];
      float4 x1 = *(const float4*)&qxe[bin*32 + gg*8 + 4];
      float4 y0 = *(const float4*)&qye[bin*32 + gg*8];
      float4 y1 = *(const float4*)&qye[bin*32 + gg*8 + 4];
      bx[0]=f2bf(x0.x); bx[1]=f2bf(x0.y); bx[2]=f2bf(x0.z); bx[3]=f2bf(x0.w);
      bx[4]=f2bf(x1.x); bx[5]=f2bf(x1.y); bx[6]=f2bf(x1.z); bx[7]=f2bf(x1.w);
      by[0]=f2bf(y0.x); by[1]=f2bf(y0.y); by[2]=f2bf(y0.z); by[3]=f2bf(y0.w);
      by[4]=f2bf(y1.x); by[5]=f2bf(y1.y); by[6]=f2bf(y1.z); by[7]=f2bf(y1.w);
    }
    f32x4 ax0={0.f,0.f,0.f,0.f}, ay0={0.f,0.f,0.f,0.f};
    ax0 = __builtin_amdgcn_mfma_f32_16x16x32_bf16(qf0, bx, ax0, 0,0,0);
    ay0 = __builtin_amdgcn_mfma_f32_16x16x32_bf16(qf1, by, ay0, 0,0,0);
    if (bin < 50) {
#pragma unroll
      for (int rg = 0; rg < 4; ++rg) {
        TB[(gg*4+rg)*104      + bin] = f2bf(ax0[rg]);
        TB[(gg*4+rg)*104 + 52 + bin] = f2bf(ay0[rg]);
      }
    }
  }

  // row coords for bias (per rg)
  int xn[4], yn[4];
#pragma unroll
  for (int rg = 0; rg < 4; ++rg) {
    int n = r0 + gg*4 + rg;
    if (n > 0 && n <= SEQ) { xn[rg] = (n-1) % 24; yn[rg] = (n-1) / 24; }
    else { xn[rg] = 0; yn[rg] = 0; }
  }
  __syncthreads();   // b1: TB visible

  // ---- Phase A: QK^T + bias -> named score registers; NO barriers ----
  const unsigned short* kwv = &kg[qkbase + (size_t)(wave*16 + li)*DH];
#define DECLS(KT, SA) f32x4 SA;
  FOR_KT(DECLS)
#undef DECLS

#define KTSTEP(KT, SA) do {                                                   \
    const int m0_ = (KT)*64;                                                  \
    s16x8 kf0_ = *(const s16x8*)&kwv[(size_t)m0_*DH + gg*8];                  \
    s16x8 kf1_ = *(const s16x8*)&kwv[(size_t)m0_*DH + 32 + gg*8];             \
    f32x4 a0_ = {0.f,0.f,0.f,0.f};                                           \
    a0_ = __builtin_amdgcn_mfma_f32_16x16x32_bf16(qf0, kf0_, a0_, 0,0,0);     \
    a0_ = __builtin_amdgcn_mfma_f32_16x16x32_bf16(qf1, kf1_, a0_, 0,0,0);     \
    int m_ = m0_ + wave*16 + li;                                              \
    int xm_ = 0, ym_ = 0;                                                     \
    bool mv_ = (m_ > 0 && m_ < SEQ);                                          \
    if (mv_) { xm_ = (m_-1) % 24; ym_ = (m_-1) / 24; }                        \
    _Pragma("unroll")                                                         \
    for (int rg = 0; rg < 4; ++rg) {                                          \
      int nloc_ = gg*4 + rg; int n_ = r0 + nloc_;                             \
      float s_ = a0_[rg]; int xi_ = 0, yi_ = 0;                               \
      if (mv_ && n_ > 0) { xi_ = xm_ - xn[rg] + 25; yi_ = ym_ - yn[rg] + 25; }\
      s_ = (s_ + bf2f(TB[nloc_*104 + xi_]) + bf2f(TB[nloc_*104 + 52 + yi_])) * 0.125f; \
      SA[rg] = (m_ < SEQ) ? s_ : -INFINITY;                                   \
    }                                                                         \
  } while (0);
  FOR_KT(KTSTEP)
#undef KTSTEP

  // ---- Phase B: softmax (named regs) -> Ps bf16; row sums in red ----
  f32x4 mxA = s0;
#define MAXST(KT, SA) if ((KT) > 0) {                                         \
    _Pragma("unroll")                                                         \
    for (int rg = 0; rg < 4; ++rg) mxA[rg] = fmaxf(mxA[rg], SA[rg]); }
  FOR_KT(MAXST)
#undef MAXST

  float MA[4];
#pragma unroll
  for (int rg = 0; rg < 4; ++rg) {
    float mx = mxA[rg];
    mx = fmaxf(mx, __shfl_xor(mx, 1));
    mx = fmaxf(mx, __shfl_xor(mx, 2));
    mx = fmaxf(mx, __shfl_xor(mx, 4));
    mx = fmaxf(mx, __shfl_xor(mx, 8));
    if (li == 0) red[gg*4 + rg][wave] = mx;
  }
  __syncthreads();   // b2: per-wave maxes
#pragma unroll
  for (int rg = 0; rg < 4; ++rg) {
    float4 ra = *(float4*)&red[gg*4 + rg][0];
    MA[rg] = fmaxf(fmaxf(ra.x, ra.y), fmaxf(ra.z, ra.w));
  }
  __syncthreads();   // b3: max reads done before red reuse

  f32x4 LpA = {0.f,0.f,0.f,0.f};
#define PROBST(KT, SA) {                                                      \
    int col_ = (KT)*64 + wave*16 + li;                                        \
    _Pragma("unroll")                                                         \
    for (int rg = 0; rg < 4; ++rg) {                                          \
      float p_ = __expf(SA[rg] - MA[rg]);                                     \
      LpA[rg] += p_;                                                          \
      if (col_ < SW) Ps[gg*4 + rg][col_] = f2bf(p_);                          \
    } }
  FOR_KT(PROBST)
#undef PROBST

#pragma unroll
  for (int rg = 0; rg < 4; ++rg) {
    float s = LpA[rg];
    s += __shfl_xor(s, 1); s += __shfl_xor(s, 2);
    s += __shfl_xor(s, 4); s += __shfl_xor(s, 8);
    if (li == 0) red[gg*4 + rg][wave] = s;
  }
  __syncthreads();   // b4: Ps complete; red sums ready; TB dead

  // ---- Phase C: O = P.V and W = P.kaugT via MFMA from global; NO barriers --
  const unsigned short* vwv = &vtg[vtbase + (size_t)(wave*16 + li)*VTS];
  const unsigned short* ktv = &kaugT[(size_t)(wave*16 + li)*KAUGR];
  f32x4 oa0  = {0.f,0.f,0.f,0.f};
  f32x4 wacc = {0.f,0.f,0.f,0.f};
#pragma unroll
  for (int vt = 0; vt < 10; ++vt) {
    int m0 = vt*64;
    s16x8 vf0 = *(const s16x8*)&vwv[m0 + gg*8];
    s16x8 vf1 = *(const s16x8*)&vwv[m0 + 32 + gg*8];
    s16x8 kt0 = *(const s16x8*)&ktv[m0 + gg*8];
    s16x8 kt1 = *(const s16x8*)&ktv[m0 + 32 + gg*8];
    s16x8 af00, af01;
    if (vt < 9) {
      af00 = *(const s16x8*)&Ps[li][m0 + gg*8];
      af01 = *(const s16x8*)&Ps[li][m0 + 32 + gg*8];
    } else {
      af00 = (gg == 0) ? *(const s16x8*)&Ps[li][576] : z8;   // probs 577..583 = 0
      af01 = z8;
    }
    oa0  = __builtin_amdgcn_mfma_f32_16x16x32_bf16(af00, vf0, oa0, 0,0,0);
    oa0  = __builtin_amdgcn_mfma_f32_16x16x32_bf16(af01, vf1, oa0, 0,0,0);
    wacc = __builtin_amdgcn_mfma_f32_16x16x32_bf16(af00, kt0, wacc, 0,0,0);
    wacc = __builtin_amdgcn_mfma_f32_16x16x32_bf16(af01, kt1, wacc, 0,0,0);
  }
#pragma unroll
  for (int rg = 0; rg < 4; ++rg)
    Wf[(gg*4 + rg)*68 + wave*16 + li] = wacc[rg];
  __syncthreads();   // b5: Wf ready

  // ---- build Wrel[r][j]: per-row shift of W into relative bins (x: j 0..49,
  //      y: j 64..113). j==0/64 carry the cls term (n==0: full row sum Lr). ----
  for (int task = tid; task < TRB*128; task += 256) {
    int r = task >> 7, j = task & 127;
    int nn = r0 + r;
    float v = 0.f;
    if (j == 0 || j == 64) {
      if (nn == 0) { float4 r4 = *(float4*)&red[r][0]; v = r4.x + r4.y + r4.z + r4.w; }
      else         v = Wf[r*68 + 48 + (j >> 6)];
    } else if (j < 50) {
      if (nn > 0) {
        int xn_ = (nn < SEQ) ? (nn-1) % 24 : 0;
        int c = j + xn_ - 25;
        if (c >= 0 && c < 24) v = Wf[r*68 + c];
      }
    } else if (j >= 65 && j < 114) {
      if (nn > 0) {
        int yn_ = (nn < SEQ) ? (nn-1) / 24 : 0;
        int c = (j - 64) + yn_ - 25;
        if (c >= 0 && c < 24) v = Wf[r*68 + 24 + c];
      }
    }
    Wrel[r*136 + j] = f2bf(v);
  }
  __syncthreads();   // b6: Wrel ready

  // ---- v-bias via K=128 MFMA: bias[n][d] = sum_j Wrel[n][j]*VTT[j][d];
  //      then epilogue: o = (oa0 + bias)/Lr, write bf16 (B,N,H,D) ----
  {
    const unsigned short* vtw = &vtt[(size_t)(wave*16 + li)*128];
    f32x4 bacc = {0.f,0.f,0.f,0.f};
#pragma unroll
    for (int ko = 0; ko < 4; ++ko) {
      s16x8 wa = *(const s16x8*)&Wrel[li*136 + ko*32 + gg*8];
      s16x8 wb = *(const s16x8*)&vtw[ko*32 + gg*8];
      bacc = __builtin_amdgcn_mfma_f32_16x16x32_bf16(wa, wb, bacc, 0,0,0);
    }
    int d = wave*16 + li;
    int bI = bh / NH, hI = bh - bI*NH;
#pragma unroll
    for (int rg = 0; rg < 4; ++rg) {
      int nloc = gg*4 + rg;
      int n = r0 + nloc;
      if (n >= SEQ) continue;
      float4 r4 = *(float4*)&red[nloc][0];
      float Lr = r4.x + r4.y + r4.z + r4.w;
      og[(((size_t)bI*SEQ + n)*NH + hI)*DH + d] = f2bf((oa0[rg] + bacc[rg]) / Lr);
    }
  }
}

// ---------------------------------------------------------------------------
// ws (ushorts): q 3.545M, k 3.545M, vt 3.637M, ows 3.545M, xbf 3.545M,
// wqkv 1.769M, wproj 0.590M, kaugT 40960, vtt 8192
// => ~40.4 MB total (< 56.7 MB proven budget).
// ---------------------------------------------------------------------------
extern "C" void kernel_launch(void* const* d_in, const int* in_sizes, int n_in,
                              void* d_out, int out_size, void* d_ws, size_t ws_size,
                              hipStream_t stream)
{
  const float* x     = (const float*)d_in[0];
  const float* qkvw  = (const float*)d_in[1];
  const float* projw = (const float*)d_in[2];
  const float* qxe   = (const float*)d_in[3];
  const float* qye   = (const float*)d_in[4];
  const float* vxe   = (const float*)d_in[5];
  const float* vye   = (const float*)d_in[6];
  float* out = (float*)d_out;

  const size_t SLc = (size_t)BHC * SEQ * DH;        // 3,545,088
  const size_t VTL = (size_t)BHC * DH * VTS;        // 3,637,248
  unsigned short* qws     = (unsigned short*)d_ws;
  unsigned short* kws     = qws + SLc;
  unsigned short* vtws    = kws + SLc;
  unsigned short* ows     = vtws + VTL;
  unsigned short* xbf     = ows + SLc;
  unsigned short* wqkv    = xbf + SLc;
  unsigned short* wproj   = wqkv + (size_t)3*EMB*EMB;
  unsigned short* kaugTws = wproj + (size_t)EMB*EMB;
  unsigned short* vttws   = kaugTws + (size_t)64*KAUGR;

  cast_kernel<<<(3*EMB*EMB/4 + 255)/256, 256, 0, stream>>>(qkvw, wqkv, 3*EMB*EMB/4);
  cast_kernel<<<(EMB*EMB/4 + 255)/256, 256, 0, stream>>>(projw, wproj, EMB*EMB/4);
  build_tables_kernel<<<(KAUGR*64 + 64*128 + 255)/256, 256, 0, stream>>>(
      vxe, vye, kaugTws, vttws);

  dim3 g1(3*EMB/GT, (MC + GT - 1)/GT);   // 18 x 37
  dim3 g2((SEQ + TRB - 1)/TRB, BHC);     // 37 x 96
  dim3 g3(EMB/GT, (MC + GT - 1)/GT);     // 6 x 37

  for (int c = 0; c < NC; ++c) {
    const float* xc = x   + (size_t)c * MC * EMB;
    float*       oc = out + (size_t)c * MC * EMB;
    cast_kernel<<<(MC*EMB/4 + 255)/256, 256, 0, stream>>>(xc, xbf, MC*EMB/4);
    gemm_bf16<<<g1, 256, 0, stream>>>(xbf, wqkv, qws, kws, vtws, nullptr, MC, 3*EMB, 0);
    attn_kernel<<<g2, 256, 0, stream>>>(qws, kws, vtws, qxe, qye,
                                        kaugTws, vttws, ows);
    gemm_bf16<<<g3, 256, 0, stream>>>(ows, wproj, nullptr, nullptr, nullptr, oc, MC, EMB, 1);
  }
}

// Round 3
// 445.085 us; speedup vs baseline: 1.1376x; 1.1124x over previous
//
#include <hip/hip_runtime.h>
#include <math.h>

#define SEQ 577
#define NH 12
#define DH 64
#define EMB 768
#define NBATCH 16
#define NC 2
#define BC (NBATCH/NC)
#define MC (BC*SEQ)      // 4616 rows per chunk
#define BHC (BC*NH)      // 96 (b,h) per chunk
#define VTS 592          // vt row stride in m (16 ushort aligned, >= 577)

typedef float f32x4 __attribute__((ext_vector_type(4)));
typedef short s16x8 __attribute__((ext_vector_type(8)));

__device__ __forceinline__ float bf2f(unsigned short u) {
  union { unsigned int i; float f; } c; c.i = ((unsigned int)u) << 16; return c.f;
}
__device__ __forceinline__ unsigned short f2bf(float f) {
  union { float f; unsigned int i; } c; c.f = f;
  unsigned int r = c.i + 0x7FFFu + ((c.i >> 16) & 1u);   // round-nearest-even
  return (unsigned short)(r >> 16);
}

// Async global->LDS, 16B per lane. LDS dest is wave-uniform base + lane*16.
__device__ __forceinline__ void gl_lds16(const unsigned short* g, unsigned short* l) {
  __builtin_amdgcn_global_load_lds(
      (const __attribute__((address_space(1))) unsigned int*)g,
      (__attribute__((address_space(3))) unsigned int*)l, 16, 0, 0);
}

// ---------------------------------------------------------------------------
__global__ __launch_bounds__(256) void cast_kernel(
    const float* __restrict__ s, unsigned short* __restrict__ d, int n4)
{
  int i = blockIdx.x * 256 + threadIdx.x;
  if (i < n4) {
    float4 v = *(const float4*)&s[(size_t)i*4];
    ushort4 o; o.x = f2bf(v.x); o.y = f2bf(v.y); o.z = f2bf(v.z); o.w = f2bf(v.w);
    *(ushort4*)&d[(size_t)i*4] = o;
  }
}

// ---------------------------------------------------------------------------
// bf16 MFMA GEMM (NT), m97-style global_load_lds staging (width=16).
// ---------------------------------------------------------------------------
#define GT 128
__global__ __launch_bounds__(256) void gemm_bf16(
    const unsigned short* __restrict__ A, const unsigned short* __restrict__ Bm,
    unsigned short* __restrict__ Cq, unsigned short* __restrict__ Ck,
    unsigned short* __restrict__ Cv, float* __restrict__ Cf,
    int M, int N, int mode)
{
  __shared__ __align__(16) unsigned short AsF[GT*32];
  __shared__ __align__(16) unsigned short BsF[GT*32];
  const int tid = threadIdx.x;
  const int wave = tid >> 6;
  const int lane = tid & 63;
  const int wr = wave >> 1, wc = wave & 1;
  const int li = lane & 15, g = lane >> 4;
  const int r0 = blockIdx.y * GT, c0 = blockIdx.x * GT;

  const int row1 = tid >> 2,          seg1 = tid & 3;
  const int row2 = (tid + 256) >> 2,  seg2 = tid & 3;
  const unsigned short* ga1 = &A [(size_t)(r0 + row1)*EMB + seg1*8];
  const unsigned short* ga2 = &A [(size_t)(r0 + row2)*EMB + seg2*8];
  const unsigned short* gb1 = &Bm[(size_t)(c0 + row1)*EMB + seg1*8];
  const unsigned short* gb2 = &Bm[(size_t)(c0 + row2)*EMB + seg2*8];
  unsigned short* la1 = &AsF[wave*512];
  unsigned short* la2 = &AsF[2048 + wave*512];
  unsigned short* lb1 = &BsF[wave*512];
  unsigned short* lb2 = &BsF[2048 + wave*512];

  f32x4 acc[4][4];
#pragma unroll
  for (int i = 0; i < 4; ++i)
#pragma unroll
    for (int j = 0; j < 4; ++j) { acc[i][j][0]=0.f; acc[i][j][1]=0.f; acc[i][j][2]=0.f; acc[i][j][3]=0.f; }

  for (int k0 = 0; k0 < EMB; k0 += 32) {
    gl_lds16(ga1 + k0, la1);
    gl_lds16(ga2 + k0, la2);
    gl_lds16(gb1 + k0, lb1);
    gl_lds16(gb2 + k0, lb2);
    __syncthreads();   // drains vmcnt incl. global_load_lds

    s16x8 af[4], bfv[4];
#pragma unroll
    for (int i = 0; i < 4; ++i) af[i]  = *(const s16x8*)&AsF[(wr*64 + i*16 + li)*32 + g*8];
#pragma unroll
    for (int j = 0; j < 4; ++j) bfv[j] = *(const s16x8*)&BsF[(wc*64 + j*16 + li)*32 + g*8];
#pragma unroll
    for (int i = 0; i < 4; ++i)
#pragma unroll
      for (int j = 0; j < 4; ++j)
        acc[i][j] = __builtin_amdgcn_mfma_f32_16x16x32_bf16(af[i], bfv[j], acc[i][j], 0, 0, 0);
    __syncthreads();
  }

#pragma unroll
  for (int i = 0; i < 4; ++i) {
    int rbase = r0 + wr*64 + i*16 + g*4;
#pragma unroll
    for (int j = 0; j < 4; ++j) {
      int col = c0 + wc*64 + j*16 + li;
#pragma unroll
      for (int rg = 0; rg < 4; ++rg) {
        int gr = rbase + rg;
        if (gr >= M) continue;
        float val = acc[i][j][rg];
        if (mode == 1) {
          Cf[(size_t)gr*N + col] = val;
        } else {
          int t  = col / EMB;
          int ct = col - t*EMB;
          int h  = ct >> 6, dd = ct & 63;
          int brow = gr / SEQ, nrow = gr - brow*SEQ;
          if (t == 0)
            Cq[(((size_t)brow*NH + h)*SEQ + nrow)*DH + dd] = f2bf(val);
          else if (t == 1)
            Ck[(((size_t)brow*NH + h)*SEQ + nrow)*DH + dd] = f2bf(val);
          else
            Cv[(((size_t)brow*NH + h)*DH + dd)*VTS + nrow] = f2bf(val);
        }
      }
    }
  }
}

// ---------------------------------------------------------------------------
// MFMA fused attention — round-0 (110us proven) structure + latency fixes:
//  * Phase A: manual 1-deep software pipeline of K frags (kp0/kp1): step t's
//    MFMA+bias VALU hides step t+1's ~200cyc L2 load. Compiler wasn't doing
//    this (VGPR=92 had no prefetch regs).
//  * Phase C: same for V frags (global) AND Ps A-frags (LDS ~120cyc); step-0
//    V frags issued right after phase A, riding through softmax for free.
//  * TB stride 100 -> 104 (y half at +52): de-alias gather banks.
// LDS: Ps 18688 + TBCS 3392 + red 256 + VXL/VYL 12800 = 35136 -> 4 blocks/CU.
// ---------------------------------------------------------------------------
#define TRB 16
#define SW 584

#define FOR_KT(X) X(0,s0) X(1,s1) X(2,s2) X(3,s3) X(4,s4) \
                  X(5,s5) X(6,s6) X(7,s7) X(8,s8) X(9,s9)

__global__ __launch_bounds__(256) void attn_kernel(
    const unsigned short* __restrict__ qg, const unsigned short* __restrict__ kg,
    const unsigned short* __restrict__ vtg,
    const float* __restrict__ qxe, const float* __restrict__ qye,
    const float* __restrict__ vxe, const float* __restrict__ vye,
    unsigned short* __restrict__ og)
{
  __shared__ __align__(16) unsigned short Ps[TRB][SW];
  __shared__ __align__(16) unsigned char  TBCS[3392];
  __shared__ __align__(16) float red[TRB][4];
  __shared__ __align__(16) float VXL[50*32];
  __shared__ __align__(16) float VYL[50*32];

  const int tid  = threadIdx.x;
  const int wave = tid >> 6, lane = tid & 63;
  const int li = lane & 15, gg = lane >> 4;
  const int bh = blockIdx.y;
  const int r0 = blockIdx.x * TRB;
  const size_t qkbase = (size_t)bh * SEQ * DH;
  const size_t vtbase = (size_t)bh * DH * VTS;
  const s16x8 z8 = {0,0,0,0,0,0,0,0};

  // ---- stage v-bias tables into LDS (1600 floats each) ----
  for (int t4 = tid; t4 < 400; t4 += 256) {
    ((float4*)VXL)[t4] = ((const float4*)vxe)[t4];
    ((float4*)VYL)[t4] = ((const float4*)vye)[t4];
  }

  // ---- Q A-frags from global (kept resident through phase A) ----
  s16x8 qf0, qf1;
  {
    int n = r0 + li;
    qf0 = (n < SEQ) ? *(const s16x8*)&qg[qkbase + (size_t)n*DH + gg*8] : z8;
    qf1 = (n < SEQ) ? *(const s16x8*)&qg[qkbase + (size_t)n*DH + 32 + gg*8] : z8;
  }

  // ---- early K step-0 prefetch (lands during TB build / barrier 1) ----
  const unsigned short* kwv = &kg[qkbase + (size_t)(wave*16 + li)*DH];
  s16x8 kp0 = *(const s16x8*)&kwv[gg*8];
  s16x8 kp1 = *(const s16x8*)&kwv[32 + gg*8];

  // ---- bias dot tables via MFMA: qx_dot/qy_dot [16 rows][50 bins] bf16,
  //      row stride 104, y half at +52 (bank de-alias) ----
  unsigned short* TB = (unsigned short*)TBCS;
  {
    int bin = wave*16 + li;
    s16x8 bx = z8, by = z8;
    if (bin < 50) {
      float4 x0 = *(const float4*)&qxe[bin*32 + gg*8];
      float4 x1 = *(const float4*)&qxe[bin*32 + gg*8 + 4];
      float4 y0 = *(const float4*)&qye[bin*32 + gg*8];
      float4 y1 = *(const float4*)&qye[bin*32 + gg*8 + 4];
      bx[0]=f2bf(x0.x); bx[1]=f2bf(x0.y); bx[2]=f2bf(x0.z); bx[3]=f2bf(x0.w);
      bx[4]=f2bf(x1.x); bx[5]=f2bf(x1.y); bx[6]=f2bf(x1.z); bx[7]=f2bf(x1.w);
      by[0]=f2bf(y0.x); by[1]=f2bf(y0.y); by[2]=f2bf(y0.z); by[3]=f2bf(y0.w);
      by[4]=f2bf(y1.x); by[5]=f2bf(y1.y); by[6]=f2bf(y1.z); by[7]=f2bf(y1.w);
    }
    f32x4 ax0={0.f,0.f,0.f,0.f}, ay0={0.f,0.f,0.f,0.f};
    ax0 = __builtin_amdgcn_mfma_f32_16x16x32_bf16(qf0, bx, ax0, 0,0,0);
    ay0 = __builtin_amdgcn_mfma_f32_16x16x32_bf16(qf1, by, ay0, 0,0,0);
    if (bin < 50) {
#pragma unroll
      for (int rg = 0; rg < 4; ++rg) {
        TB[(gg*4+rg)*104      + bin] = f2bf(ax0[rg]);
        TB[(gg*4+rg)*104 + 52 + bin] = f2bf(ay0[rg]);
      }
    }
  }

  // row coords for bias (per rg)
  int xn[4], yn[4];
#pragma unroll
  for (int rg = 0; rg < 4; ++rg) {
    int n = r0 + gg*4 + rg;
    if (n > 0 && n <= SEQ) { xn[rg] = (n-1) % 24; yn[rg] = (n-1) / 24; }
    else { xn[rg] = 0; yn[rg] = 0; }
  }
  __syncthreads();   // barrier 1: TB + VXL/VYL visible

  // ---- Phase A: QK^T + bias -> named score registers; K pipelined ----
#define DECLS(KT, SA) f32x4 SA;
  FOR_KT(DECLS)
#undef DECLS

#define KTSTEP(KT, SA) do {                                                   \
    const int m0_ = (KT)*64;                                                  \
    s16x8 kc0_ = kp0, kc1_ = kp1;                                             \
    if ((KT) < 9) {                                                           \
      kp0 = *(const s16x8*)&kwv[(size_t)(m0_ + 64)*DH + gg*8];                \
      kp1 = *(const s16x8*)&kwv[(size_t)(m0_ + 64)*DH + 32 + gg*8];           \
    }                                                                         \
    f32x4 a0_ = {0.f,0.f,0.f,0.f};                                            \
    a0_ = __builtin_amdgcn_mfma_f32_16x16x32_bf16(qf0, kc0_, a0_, 0,0,0);     \
    a0_ = __builtin_amdgcn_mfma_f32_16x16x32_bf16(qf1, kc1_, a0_, 0,0,0);     \
    int m_ = m0_ + wave*16 + li;                                              \
    int xm_ = 0, ym_ = 0;                                                     \
    bool mv_ = (m_ > 0 && m_ < SEQ);                                          \
    if (mv_) { xm_ = (m_-1) % 24; ym_ = (m_-1) / 24; }                        \
    _Pragma("unroll")                                                         \
    for (int rg = 0; rg < 4; ++rg) {                                          \
      int nloc_ = gg*4 + rg; int n_ = r0 + nloc_;                             \
      float s_ = a0_[rg]; int xi_ = 0, yi_ = 0;                               \
      if (mv_ && n_ > 0) { xi_ = xm_ - xn[rg] + 25; yi_ = ym_ - yn[rg] + 25; }\
      s_ = (s_ + bf2f(TB[nloc_*104 + xi_]) + bf2f(TB[nloc_*104 + 52 + yi_])) * 0.125f; \
      SA[rg] = (m_ < SEQ) ? s_ : -INFINITY;                                   \
    }                                                                         \
  } while (0);
  FOR_KT(KTSTEP)
#undef KTSTEP

  // ---- early V step-0 prefetch (rides through softmax phase) ----
  const unsigned short* vwv = &vtg[vtbase + (size_t)(wave*16 + li)*VTS];
  s16x8 vp0 = *(const s16x8*)&vwv[gg*8];
  s16x8 vp1 = *(const s16x8*)&vwv[32 + gg*8];

  // ---- Phase B: softmax (named regs) -> Ps bf16; col/row sums + L ----
  f32x4 mxA = s0;
#define MAXST(KT, SA) if ((KT) > 0) {                                         \
    _Pragma("unroll")                                                         \
    for (int rg = 0; rg < 4; ++rg) mxA[rg] = fmaxf(mxA[rg], SA[rg]); }
  FOR_KT(MAXST)
#undef MAXST

  float MA[4];
#pragma unroll
  for (int rg = 0; rg < 4; ++rg) {
    float mx = mxA[rg];
    mx = fmaxf(mx, __shfl_xor(mx, 1));
    mx = fmaxf(mx, __shfl_xor(mx, 2));
    mx = fmaxf(mx, __shfl_xor(mx, 4));
    mx = fmaxf(mx, __shfl_xor(mx, 8));
    if (li == 0) red[gg*4 + rg][wave] = mx;
  }
  __syncthreads();   // barrier 2: per-wave maxes
#pragma unroll
  for (int rg = 0; rg < 4; ++rg) {
    float4 ra = *(float4*)&red[gg*4 + rg][0];
    MA[rg] = fmaxf(fmaxf(ra.x, ra.y), fmaxf(ra.z, ra.w));
  }
  __syncthreads();   // barrier 3: max reads done before red reuse

  f32x4 LpA = {0.f,0.f,0.f,0.f};
#define PROBST(KT, SA) {                                                      \
    int col_ = (KT)*64 + wave*16 + li;                                        \
    _Pragma("unroll")                                                         \
    for (int rg = 0; rg < 4; ++rg) {                                          \
      float p_ = __expf(SA[rg] - MA[rg]);                                     \
      LpA[rg] += p_;                                                          \
      if (col_ < SW) Ps[gg*4 + rg][col_] = f2bf(p_);                          \
    } }
  FOR_KT(PROBST)
#undef PROBST

#pragma unroll
  for (int rg = 0; rg < 4; ++rg) {
    float s = LpA[rg];
    s += __shfl_xor(s, 1); s += __shfl_xor(s, 2);
    s += __shfl_xor(s, 4); s += __shfl_xor(s, 8);
    if (li == 0) red[gg*4 + rg][wave] = s;
  }
  __syncthreads();   // barrier 4: Ps complete; red sums ready
  float* CS = (float*)TBCS;                            // [16][49]; TB is dead
  if (wave == 0 && li == 0) {
#pragma unroll
    for (int rg = 0; rg < 4; ++rg) {
      int nloc = gg*4 + rg;
      float4 r4 = *(float4*)&red[nloc][0];
      CS[nloc*49 + 48] = r4.x + r4.y + r4.z + r4.w;
    }
  }
  for (int task = tid; task < TRB*48; task += 256) {
    int r = task / 48, k = task - (task/48)*48;
    float s = 0.f;
    if (k < 24) {
#pragma unroll
      for (int c2 = 0; c2 < 24; ++c2) s += bf2f(Ps[r][1 + c2*24 + k]);
    } else {
      int rw = k - 24;
#pragma unroll
      for (int c2 = 0; c2 < 24; ++c2) s += bf2f(Ps[r][1 + rw*24 + c2]);
    }
    CS[r*49 + k] = s;
  }
  __syncthreads();   // barrier 5: CS complete (epilogue reads it)

  // ---- Phase C: O = P.V via MFMA, V + Ps pipelined; NO barriers ----
  f32x4 oa0 = {0.f,0.f,0.f,0.f};
  s16x8 ap0 = *(const s16x8*)&Ps[li][gg*8];
  s16x8 ap1 = *(const s16x8*)&Ps[li][32 + gg*8];
#pragma unroll
  for (int vt = 0; vt < 10; ++vt) {
    s16x8 vc0 = vp0, vc1 = vp1;
    s16x8 ac0 = ap0, ac1 = ap1;
    if (vt < 9) {
      int mn = (vt + 1)*64;
      vp0 = *(const s16x8*)&vwv[mn + gg*8];
      vp1 = *(const s16x8*)&vwv[mn + 32 + gg*8];
      if (vt < 8) {
        ap0 = *(const s16x8*)&Ps[li][mn + gg*8];
        ap1 = *(const s16x8*)&Ps[li][mn + 32 + gg*8];
      } else {
        ap0 = (gg == 0) ? *(const s16x8*)&Ps[li][576] : z8;   // probs 577..583 = 0
        ap1 = z8;
      }
    }
    oa0 = __builtin_amdgcn_mfma_f32_16x16x32_bf16(ac0, vc0, oa0, 0,0,0);
    oa0 = __builtin_amdgcn_mfma_f32_16x16x32_bf16(ac1, vc1, oa0, 0,0,0);
  }

  // ---- Epilogue: + v-bias (from LDS tables), /L, write bf16 (B,N,H,D) ----
  {
    int d = wave*16 + li;
    const float* tabL = (d < 32) ? VXL : VYL;
    int dd = d & 31;
    bool useX = (d < 32);
    int bI = bh / NH, hI = bh - bI*NH;
#pragma unroll
    for (int rg = 0; rg < 4; ++rg) {
      int nloc = gg*4 + rg;
      int n = r0 + nloc;
      if (n >= SEQ) continue;
      float Lr = CS[nloc*49 + 48];
      float bias;
      if (n == 0) {
        bias = Lr * tabL[dd];
      } else {
        int cn = useX ? ((n-1) % 24) : ((n-1) / 24);
        bias = bf2f(Ps[nloc][0]) * tabL[dd];
#pragma unroll
        for (int c = 0; c < 24; ++c) {
          float w = CS[nloc*49 + (useX ? c : 24 + c)];
          bias = fmaf(w, tabL[(c - cn + 25)*32 + dd], bias);
        }
      }
      float o = (oa0[rg] + bias) / Lr;
      og[(((size_t)bI*SEQ + n)*NH + hI)*DH + d] = f2bf(o);
    }
  }
}

// ---------------------------------------------------------------------------
// ws (ushorts): q 3.545M, k 3.545M, vt 3.637M, ows 3.545M, xbf 3.545M,
// wqkv 1.769M, wproj 0.590M  => 40.35 MB total (< 56.7 MB proven budget).
// ---------------------------------------------------------------------------
extern "C" void kernel_launch(void* const* d_in, const int* in_sizes, int n_in,
                              void* d_out, int out_size, void* d_ws, size_t ws_size,
                              hipStream_t stream)
{
  const float* x     = (const float*)d_in[0];
  const float* qkvw  = (const float*)d_in[1];
  const float* projw = (const float*)d_in[2];
  const float* qxe   = (const float*)d_in[3];
  const float* qye   = (const float*)d_in[4];
  const float* vxe   = (const float*)d_in[5];
  const float* vye   = (const float*)d_in[6];
  float* out = (float*)d_out;

  const size_t SLc = (size_t)BHC * SEQ * DH;        // 3,545,088
  const size_t VTL = (size_t)BHC * DH * VTS;        // 3,637,248
  unsigned short* qws   = (unsigned short*)d_ws;
  unsigned short* kws   = qws + SLc;
  unsigned short* vtws  = kws + SLc;
  unsigned short* ows   = vtws + VTL;
  unsigned short* xbf   = ows + SLc;
  unsigned short* wqkv  = xbf + SLc;
  unsigned short* wproj = wqkv + (size_t)3*EMB*EMB;

  cast_kernel<<<(3*EMB*EMB/4 + 255)/256, 256, 0, stream>>>(qkvw, wqkv, 3*EMB*EMB/4);
  cast_kernel<<<(EMB*EMB/4 + 255)/256, 256, 0, stream>>>(projw, wproj, EMB*EMB/4);

  dim3 g1(3*EMB/GT, (MC + GT - 1)/GT);   // 18 x 37
  dim3 g2((SEQ + TRB - 1)/TRB, BHC);     // 37 x 96
  dim3 g3(EMB/GT, (MC + GT - 1)/GT);     // 6 x 37

  for (int c = 0; c < NC; ++c) {
    const float* xc = x   + (size_t)c * MC * EMB;
    float*       oc = out + (size_t)c * MC * EMB;
    cast_kernel<<<(MC*EMB/4 + 255)/256, 256, 0, stream>>>(xc, xbf, MC*EMB/4);
    gemm_bf16<<<g1, 256, 0, stream>>>(xbf, wqkv, qws, kws, vtws, nullptr, MC, 3*EMB, 0);
    attn_kernel<<<g2, 256, 0, stream>>>(qws, kws, vtws, qxe, qye, vxe, vye, ows);
    gemm_bf16<<<g3, 256, 0, stream>>>(ows, wproj, nullptr, nullptr, nullptr, oc, MC, EMB, 1);
  }
}

// Round 4
// 443.222 us; speedup vs baseline: 1.1424x; 1.0042x over previous
//
#include <hip/hip_runtime.h>
#include <math.h>

#define SEQ 577
#define NH 12
#define DH 64
#define EMB 768
#define NBATCH 16
#define NC 2
#define BC (NBATCH/NC)
#define MC (BC*SEQ)      // 4616 rows per chunk
#define BHC (BC*NH)      // 96 (b,h) per chunk
#define VTS 592          // vt row stride in m (16 ushort aligned, >= 577)

typedef float f32x4 __attribute__((ext_vector_type(4)));
typedef short s16x8 __attribute__((ext_vector_type(8)));

__device__ __forceinline__ float bf2f(unsigned short u) {
  union { unsigned int i; float f; } c; c.i = ((unsigned int)u) << 16; return c.f;
}
__device__ __forceinline__ unsigned short f2bf(float f) {
  union { float f; unsigned int i; } c; c.f = f;
  unsigned int r = c.i + 0x7FFFu + ((c.i >> 16) & 1u);   // round-nearest-even
  return (unsigned short)(r >> 16);
}

// Async global->LDS, 16B per lane. LDS dest is wave-uniform base + lane*16.
__device__ __forceinline__ void gl_lds16(const unsigned short* g, unsigned short* l) {
  __builtin_amdgcn_global_load_lds(
      (const __attribute__((address_space(1))) unsigned int*)g,
      (__attribute__((address_space(3))) unsigned int*)l, 16, 0, 0);
}

// ---------------------------------------------------------------------------
__global__ __launch_bounds__(256) void cast_kernel(
    const float* __restrict__ s, unsigned short* __restrict__ d, int n4)
{
  int i = blockIdx.x * 256 + threadIdx.x;
  if (i < n4) {
    float4 v = *(const float4*)&s[(size_t)i*4];
    ushort4 o; o.x = f2bf(v.x); o.y = f2bf(v.y); o.z = f2bf(v.z); o.w = f2bf(v.w);
    *(ushort4*)&d[(size_t)i*4] = o;
  }
}

// ---------------------------------------------------------------------------
// bf16 MFMA GEMM (NT), m97-style global_load_lds staging (width=16).
// Scatter epilogue hoisted: per-j column decomposition (t,h,dd) computed 4x
// instead of 64x; per-(i,rg) row decomposition (brow,nrow) 16x instead of 64x.
// ---------------------------------------------------------------------------
#define GT 128
__global__ __launch_bounds__(256) void gemm_bf16(
    const unsigned short* __restrict__ A, const unsigned short* __restrict__ Bm,
    unsigned short* __restrict__ Cq, unsigned short* __restrict__ Ck,
    unsigned short* __restrict__ Cv, float* __restrict__ Cf,
    int M, int N, int mode)
{
  __shared__ __align__(16) unsigned short AsF[GT*32];
  __shared__ __align__(16) unsigned short BsF[GT*32];
  const int tid = threadIdx.x;
  const int wave = tid >> 6;
  const int lane = tid & 63;
  const int wr = wave >> 1, wc = wave & 1;
  const int li = lane & 15, g = lane >> 4;
  const int r0 = blockIdx.y * GT, c0 = blockIdx.x * GT;

  const int row1 = tid >> 2,          seg1 = tid & 3;
  const int row2 = (tid + 256) >> 2,  seg2 = tid & 3;
  const unsigned short* ga1 = &A [(size_t)(r0 + row1)*EMB + seg1*8];
  const unsigned short* ga2 = &A [(size_t)(r0 + row2)*EMB + seg2*8];
  const unsigned short* gb1 = &Bm[(size_t)(c0 + row1)*EMB + seg1*8];
  const unsigned short* gb2 = &Bm[(size_t)(c0 + row2)*EMB + seg2*8];
  unsigned short* la1 = &AsF[wave*512];
  unsigned short* la2 = &AsF[2048 + wave*512];
  unsigned short* lb1 = &BsF[wave*512];
  unsigned short* lb2 = &BsF[2048 + wave*512];

  f32x4 acc[4][4];
#pragma unroll
  for (int i = 0; i < 4; ++i)
#pragma unroll
    for (int j = 0; j < 4; ++j) { acc[i][j][0]=0.f; acc[i][j][1]=0.f; acc[i][j][2]=0.f; acc[i][j][3]=0.f; }

  for (int k0 = 0; k0 < EMB; k0 += 32) {
    gl_lds16(ga1 + k0, la1);
    gl_lds16(ga2 + k0, la2);
    gl_lds16(gb1 + k0, lb1);
    gl_lds16(gb2 + k0, lb2);
    __syncthreads();   // drains vmcnt incl. global_load_lds

    s16x8 af[4], bfv[4];
#pragma unroll
    for (int i = 0; i < 4; ++i) af[i]  = *(const s16x8*)&AsF[(wr*64 + i*16 + li)*32 + g*8];
#pragma unroll
    for (int j = 0; j < 4; ++j) bfv[j] = *(const s16x8*)&BsF[(wc*64 + j*16 + li)*32 + g*8];
#pragma unroll
    for (int i = 0; i < 4; ++i)
#pragma unroll
      for (int j = 0; j < 4; ++j)
        acc[i][j] = __builtin_amdgcn_mfma_f32_16x16x32_bf16(af[i], bfv[j], acc[i][j], 0, 0, 0);
    __syncthreads();
  }

  if (mode == 1) {
#pragma unroll
    for (int i = 0; i < 4; ++i) {
      int rbase = r0 + wr*64 + i*16 + g*4;
#pragma unroll
      for (int rg = 0; rg < 4; ++rg) {
        int gr = rbase + rg;
        if (gr >= M) continue;
        float* crow = &Cf[(size_t)gr*N + c0 + wc*64 + li];
#pragma unroll
        for (int j = 0; j < 4; ++j) crow[j*16] = acc[i][j][rg];
      }
    }
  } else {
    // per-j column decomposition (wave-uniform t per j within a block)
    unsigned short* cb[4]; size_t coff[4]; int vj[4];
#pragma unroll
    for (int j = 0; j < 4; ++j) {
      int col = c0 + wc*64 + j*16 + li;
      int t  = col / EMB;
      int ct = col - t*EMB;
      int h  = ct >> 6, dd = ct & 63;
      if (t == 2) { cb[j] = Cv; coff[j] = ((size_t)h*DH + dd)*VTS; vj[j] = 1; }
      else        { cb[j] = (t == 0) ? Cq : Ck;
                    coff[j] = (size_t)h*SEQ*DH + dd; vj[j] = 0; }
    }
#pragma unroll
    for (int i = 0; i < 4; ++i) {
      int rbase = r0 + wr*64 + i*16 + g*4;
#pragma unroll
      for (int rg = 0; rg < 4; ++rg) {
        int gr = rbase + rg;
        if (gr >= M) continue;
        int brow = gr / SEQ, nrow = gr - brow*SEQ;
        size_t roffQK = ((size_t)brow*NH)*SEQ*DH + (size_t)nrow*DH;
        size_t roffV  = ((size_t)brow*NH)*DH*VTS + (size_t)nrow;
#pragma unroll
        for (int j = 0; j < 4; ++j)
          cb[j][(vj[j] ? roffV : roffQK) + coff[j]] = f2bf(acc[i][j][rg]);
      }
    }
  }
}

// ---------------------------------------------------------------------------
// MFMA fused attention — round-3 structure + occupancy/chain fixes:
//  * VXL/VYL stored bf16 (6400 B, was 12800 f32): LDS 35328 -> 28736 ->
//    5 blocks/CU (was 4). Rounds 1-2 proved bf16 v-tables don't move absmax.
//  * Epilogue: 4 independent partial accumulators (fmaf chain 24 -> 6) +
//    hoisted row pointers.
//  * Phase A/C 1-deep software pipelines kept (round-3, −4us).
// LDS: Ps 18688 + TBCS 3392 + red 256 + VXL/VYL 6400 = 28736 -> 5 blocks/CU.
// ---------------------------------------------------------------------------
#define TRB 16
#define SW 584

#define FOR_KT(X) X(0,s0) X(1,s1) X(2,s2) X(3,s3) X(4,s4) \
                  X(5,s5) X(6,s6) X(7,s7) X(8,s8) X(9,s9)

__global__ __launch_bounds__(256) void attn_kernel(
    const unsigned short* __restrict__ qg, const unsigned short* __restrict__ kg,
    const unsigned short* __restrict__ vtg,
    const float* __restrict__ qxe, const float* __restrict__ qye,
    const float* __restrict__ vxe, const float* __restrict__ vye,
    unsigned short* __restrict__ og)
{
  __shared__ __align__(16) unsigned short Ps[TRB][SW];
  __shared__ __align__(16) unsigned char  TBCS[3392];
  __shared__ __align__(16) float red[TRB][4];
  __shared__ __align__(16) unsigned short VXL[50*32];
  __shared__ __align__(16) unsigned short VYL[50*32];

  const int tid  = threadIdx.x;
  const int wave = tid >> 6, lane = tid & 63;
  const int li = lane & 15, gg = lane >> 4;
  const int bh = blockIdx.y;
  const int r0 = blockIdx.x * TRB;
  const size_t qkbase = (size_t)bh * SEQ * DH;
  const size_t vtbase = (size_t)bh * DH * VTS;
  const s16x8 z8 = {0,0,0,0,0,0,0,0};

  // ---- stage v-bias tables into LDS as bf16 (1600 entries each) ----
  for (int t4 = tid; t4 < 400; t4 += 256) {
    float4 a = ((const float4*)vxe)[t4];
    float4 b = ((const float4*)vye)[t4];
    ushort4 oa; oa.x=f2bf(a.x); oa.y=f2bf(a.y); oa.z=f2bf(a.z); oa.w=f2bf(a.w);
    ushort4 ob; ob.x=f2bf(b.x); ob.y=f2bf(b.y); ob.z=f2bf(b.z); ob.w=f2bf(b.w);
    ((ushort4*)VXL)[t4] = oa;
    ((ushort4*)VYL)[t4] = ob;
  }

  // ---- Q A-frags from global (kept resident through phase A) ----
  s16x8 qf0, qf1;
  {
    int n = r0 + li;
    qf0 = (n < SEQ) ? *(const s16x8*)&qg[qkbase + (size_t)n*DH + gg*8] : z8;
    qf1 = (n < SEQ) ? *(const s16x8*)&qg[qkbase + (size_t)n*DH + 32 + gg*8] : z8;
  }

  // ---- early K step-0 prefetch (lands during TB build / barrier 1) ----
  const unsigned short* kwv = &kg[qkbase + (size_t)(wave*16 + li)*DH];
  s16x8 kp0 = *(const s16x8*)&kwv[gg*8];
  s16x8 kp1 = *(const s16x8*)&kwv[32 + gg*8];

  // ---- bias dot tables via MFMA: qx_dot/qy_dot [16 rows][50 bins] bf16,
  //      row stride 104, y half at +52 (bank de-alias) ----
  unsigned short* TB = (unsigned short*)TBCS;
  {
    int bin = wave*16 + li;
    s16x8 bx = z8, by = z8;
    if (bin < 50) {
      float4 x0 = *(const float4*)&qxe[bin*32 + gg*8];
      float4 x1 = *(const float4*)&qxe[bin*32 + gg*8 + 4];
      float4 y0 = *(const float4*)&qye[bin*32 + gg*8];
      float4 y1 = *(const float4*)&qye[bin*32 + gg*8 + 4];
      bx[0]=f2bf(x0.x); bx[1]=f2bf(x0.y); bx[2]=f2bf(x0.z); bx[3]=f2bf(x0.w);
      bx[4]=f2bf(x1.x); bx[5]=f2bf(x1.y); bx[6]=f2bf(x1.z); bx[7]=f2bf(x1.w);
      by[0]=f2bf(y0.x); by[1]=f2bf(y0.y); by[2]=f2bf(y0.z); by[3]=f2bf(y0.w);
      by[4]=f2bf(y1.x); by[5]=f2bf(y1.y); by[6]=f2bf(y1.z); by[7]=f2bf(y1.w);
    }
    f32x4 ax0={0.f,0.f,0.f,0.f}, ay0={0.f,0.f,0.f,0.f};
    ax0 = __builtin_amdgcn_mfma_f32_16x16x32_bf16(qf0, bx, ax0, 0,0,0);
    ay0 = __builtin_amdgcn_mfma_f32_16x16x32_bf16(qf1, by, ay0, 0,0,0);
    if (bin < 50) {
#pragma unroll
      for (int rg = 0; rg < 4; ++rg) {
        TB[(gg*4+rg)*104      + bin] = f2bf(ax0[rg]);
        TB[(gg*4+rg)*104 + 52 + bin] = f2bf(ay0[rg]);
      }
    }
  }

  // row coords for bias (per rg)
  int xn[4], yn[4];
#pragma unroll
  for (int rg = 0; rg < 4; ++rg) {
    int n = r0 + gg*4 + rg;
    if (n > 0 && n <= SEQ) { xn[rg] = (n-1) % 24; yn[rg] = (n-1) / 24; }
    else { xn[rg] = 0; yn[rg] = 0; }
  }
  __syncthreads();   // barrier 1: TB + VXL/VYL visible

  // ---- Phase A: QK^T + bias -> named score registers; K pipelined ----
#define DECLS(KT, SA) f32x4 SA;
  FOR_KT(DECLS)
#undef DECLS

#define KTSTEP(KT, SA) do {                                                   \
    const int m0_ = (KT)*64;                                                  \
    s16x8 kc0_ = kp0, kc1_ = kp1;                                             \
    if ((KT) < 9) {                                                           \
      kp0 = *(const s16x8*)&kwv[(size_t)(m0_ + 64)*DH + gg*8];                \
      kp1 = *(const s16x8*)&kwv[(size_t)(m0_ + 64)*DH + 32 + gg*8];           \
    }                                                                         \
    f32x4 a0_ = {0.f,0.f,0.f,0.f};                                            \
    a0_ = __builtin_amdgcn_mfma_f32_16x16x32_bf16(qf0, kc0_, a0_, 0,0,0);     \
    a0_ = __builtin_amdgcn_mfma_f32_16x16x32_bf16(qf1, kc1_, a0_, 0,0,0);     \
    int m_ = m0_ + wave*16 + li;                                              \
    int xm_ = 0, ym_ = 0;                                                     \
    bool mv_ = (m_ > 0 && m_ < SEQ);                                          \
    if (mv_) { xm_ = (m_-1) % 24; ym_ = (m_-1) / 24; }                        \
    _Pragma("unroll")                                                         \
    for (int rg = 0; rg < 4; ++rg) {                                          \
      int nloc_ = gg*4 + rg; int n_ = r0 + nloc_;                             \
      float s_ = a0_[rg]; int xi_ = 0, yi_ = 0;                               \
      if (mv_ && n_ > 0) { xi_ = xm_ - xn[rg] + 25; yi_ = ym_ - yn[rg] + 25; }\
      s_ = (s_ + bf2f(TB[nloc_*104 + xi_]) + bf2f(TB[nloc_*104 + 52 + yi_])) * 0.125f; \
      SA[rg] = (m_ < SEQ) ? s_ : -INFINITY;                                   \
    }                                                                         \
  } while (0);
  FOR_KT(KTSTEP)
#undef KTSTEP

  // ---- early V step-0 prefetch (rides through softmax phase) ----
  const unsigned short* vwv = &vtg[vtbase + (size_t)(wave*16 + li)*VTS];
  s16x8 vp0 = *(const s16x8*)&vwv[gg*8];
  s16x8 vp1 = *(const s16x8*)&vwv[32 + gg*8];

  // ---- Phase B: softmax (named regs) -> Ps bf16; col/row sums + L ----
  f32x4 mxA = s0;
#define MAXST(KT, SA) if ((KT) > 0) {                                         \
    _Pragma("unroll")                                                         \
    for (int rg = 0; rg < 4; ++rg) mxA[rg] = fmaxf(mxA[rg], SA[rg]); }
  FOR_KT(MAXST)
#undef MAXST

  float MA[4];
#pragma unroll
  for (int rg = 0; rg < 4; ++rg) {
    float mx = mxA[rg];
    mx = fmaxf(mx, __shfl_xor(mx, 1));
    mx = fmaxf(mx, __shfl_xor(mx, 2));
    mx = fmaxf(mx, __shfl_xor(mx, 4));
    mx = fmaxf(mx, __shfl_xor(mx, 8));
    if (li == 0) red[gg*4 + rg][wave] = mx;
  }
  __syncthreads();   // barrier 2: per-wave maxes
#pragma unroll
  for (int rg = 0; rg < 4; ++rg) {
    float4 ra = *(float4*)&red[gg*4 + rg][0];
    MA[rg] = fmaxf(fmaxf(ra.x, ra.y), fmaxf(ra.z, ra.w));
  }
  __syncthreads();   // barrier 3: max reads done before red reuse

  f32x4 LpA = {0.f,0.f,0.f,0.f};
#define PROBST(KT, SA) {                                                      \
    int col_ = (KT)*64 + wave*16 + li;                                        \
    _Pragma("unroll")                                                         \
    for (int rg = 0; rg < 4; ++rg) {                                          \
      float p_ = __expf(SA[rg] - MA[rg]);                                     \
      LpA[rg] += p_;                                                          \
      if (col_ < SW) Ps[gg*4 + rg][col_] = f2bf(p_);                          \
    } }
  FOR_KT(PROBST)
#undef PROBST

#pragma unroll
  for (int rg = 0; rg < 4; ++rg) {
    float s = LpA[rg];
    s += __shfl_xor(s, 1); s += __shfl_xor(s, 2);
    s += __shfl_xor(s, 4); s += __shfl_xor(s, 8);
    if (li == 0) red[gg*4 + rg][wave] = s;
  }
  __syncthreads();   // barrier 4: Ps complete; red sums ready
  float* CS = (float*)TBCS;                            // [16][49]; TB is dead
  if (wave == 0 && li == 0) {
#pragma unroll
    for (int rg = 0; rg < 4; ++rg) {
      int nloc = gg*4 + rg;
      float4 r4 = *(float4*)&red[nloc][0];
      CS[nloc*49 + 48] = r4.x + r4.y + r4.z + r4.w;
    }
  }
  for (int task = tid; task < TRB*48; task += 256) {
    int r = task / 48, k = task - (task/48)*48;
    float s = 0.f;
    if (k < 24) {
#pragma unroll
      for (int c2 = 0; c2 < 24; ++c2) s += bf2f(Ps[r][1 + c2*24 + k]);
    } else {
      int rw = k - 24;
#pragma unroll
      for (int c2 = 0; c2 < 24; ++c2) s += bf2f(Ps[r][1 + rw*24 + c2]);
    }
    CS[r*49 + k] = s;
  }
  __syncthreads();   // barrier 5: CS complete (epilogue reads it)

  // ---- Phase C: O = P.V via MFMA, V + Ps pipelined; NO barriers ----
  f32x4 oa0 = {0.f,0.f,0.f,0.f};
  s16x8 ap0 = *(const s16x8*)&Ps[li][gg*8];
  s16x8 ap1 = *(const s16x8*)&Ps[li][32 + gg*8];
#pragma unroll
  for (int vt = 0; vt < 10; ++vt) {
    s16x8 vc0 = vp0, vc1 = vp1;
    s16x8 ac0 = ap0, ac1 = ap1;
    if (vt < 9) {
      int mn = (vt + 1)*64;
      vp0 = *(const s16x8*)&vwv[mn + gg*8];
      vp1 = *(const s16x8*)&vwv[mn + 32 + gg*8];
      if (vt < 8) {
        ap0 = *(const s16x8*)&Ps[li][mn + gg*8];
        ap1 = *(const s16x8*)&Ps[li][mn + 32 + gg*8];
      } else {
        ap0 = (gg == 0) ? *(const s16x8*)&Ps[li][576] : z8;   // probs 577..583 = 0
        ap1 = z8;
      }
    }
    oa0 = __builtin_amdgcn_mfma_f32_16x16x32_bf16(ac0, vc0, oa0, 0,0,0);
    oa0 = __builtin_amdgcn_mfma_f32_16x16x32_bf16(ac1, vc1, oa0, 0,0,0);
  }

  // ---- Epilogue: + v-bias (bf16 LDS tables), /L, write bf16 (B,N,H,D) ----
  {
    int d = wave*16 + li;
    const unsigned short* tabL = (d < 32) ? VXL : VYL;
    int dd = d & 31;
    bool useX = (d < 32);
    int bI = bh / NH, hI = bh - bI*NH;
#pragma unroll
    for (int rg = 0; rg < 4; ++rg) {
      int nloc = gg*4 + rg;
      int n = r0 + nloc;
      if (n >= SEQ) continue;
      float Lr = CS[nloc*49 + 48];
      float bias;
      if (n == 0) {
        bias = Lr * bf2f(tabL[dd]);
      } else {
        int cn = useX ? ((n-1) % 24) : ((n-1) / 24);
        const unsigned short* trow = &tabL[(25 - cn)*32 + dd];
        const float* csrow = &CS[nloc*49 + (useX ? 0 : 24)];
        float b0 = bf2f(Ps[nloc][0]) * bf2f(tabL[dd]);
        float b1 = 0.f, b2 = 0.f, b3 = 0.f;
#pragma unroll
        for (int c = 0; c < 24; c += 4) {
          b0 = fmaf(csrow[c    ], bf2f(trow[(c    )*32]), b0);
          b1 = fmaf(csrow[c + 1], bf2f(trow[(c + 1)*32]), b1);
          b2 = fmaf(csrow[c + 2], bf2f(trow[(c + 2)*32]), b2);
          b3 = fmaf(csrow[c + 3], bf2f(trow[(c + 3)*32]), b3);
        }
        bias = (b0 + b1) + (b2 + b3);
      }
      float o = (oa0[rg] + bias) / Lr;
      og[(((size_t)bI*SEQ + n)*NH + hI)*DH + d] = f2bf(o);
    }
  }
}

// ---------------------------------------------------------------------------
// ws (ushorts): q 3.545M, k 3.545M, vt 3.637M, ows 3.545M, xbf 3.545M,
// wqkv 1.769M, wproj 0.590M  => 40.35 MB total (< 56.7 MB proven budget).
// ---------------------------------------------------------------------------
extern "C" void kernel_launch(void* const* d_in, const int* in_sizes, int n_in,
                              void* d_out, int out_size, void* d_ws, size_t ws_size,
                              hipStream_t stream)
{
  const float* x     = (const float*)d_in[0];
  const float* qkvw  = (const float*)d_in[1];
  const float* projw = (const float*)d_in[2];
  const float* qxe   = (const float*)d_in[3];
  const float* qye   = (const float*)d_in[4];
  const float* vxe   = (const float*)d_in[5];
  const float* vye   = (const float*)d_in[6];
  float* out = (float*)d_out;

  const size_t SLc = (size_t)BHC * SEQ * DH;        // 3,545,088
  const size_t VTL = (size_t)BHC * DH * VTS;        // 3,637,248
  unsigned short* qws   = (unsigned short*)d_ws;
  unsigned short* kws   = qws + SLc;
  unsigned short* vtws  = kws + SLc;
  unsigned short* ows   = vtws + VTL;
  unsigned short* xbf   = ows + SLc;
  unsigned short* wqkv  = xbf + SLc;
  unsigned short* wproj = wqkv + (size_t)3*EMB*EMB;

  cast_kernel<<<(3*EMB*EMB/4 + 255)/256, 256, 0, stream>>>(qkvw, wqkv, 3*EMB*EMB/4);
  cast_kernel<<<(EMB*EMB/4 + 255)/256, 256, 0, stream>>>(projw, wproj, EMB*EMB/4);

  dim3 g1(3*EMB/GT, (MC + GT - 1)/GT);   // 18 x 37
  dim3 g2((SEQ + TRB - 1)/TRB, BHC);     // 37 x 96
  dim3 g3(EMB/GT, (MC + GT - 1)/GT);     // 6 x 37

  for (int c = 0; c < NC; ++c) {
    const float* xc = x   + (size_t)c * MC * EMB;
    float*       oc = out + (size_t)c * MC * EMB;
    cast_kernel<<<(MC*EMB/4 + 255)/256, 256, 0, stream>>>(xc, xbf, MC*EMB/4);
    gemm_bf16<<<g1, 256, 0, stream>>>(xbf, wqkv, qws, kws, vtws, nullptr, MC, 3*EMB, 0);
    attn_kernel<<<g2, 256, 0, stream>>>(qws, kws, vtws, qxe, qye, vxe, vye, ows);
    gemm_bf16<<<g3, 256, 0, stream>>>(ows, wproj, nullptr, nullptr, nullptr, oc, MC, EMB, 1);
  }
}